// Round 6
// baseline (278.190 us; speedup 1.0000x reference)
//
#include <hip/hip_runtime.h>
#include <hip/hip_bf16.h>
#include <stdint.h>

typedef __bf16 bf16x8 __attribute__((ext_vector_type(8)));
typedef float  f32x4  __attribute__((ext_vector_type(4)));

static constexpr int Mdim = 2048;   // B*S
static constexpr int Ndim = 4096;   // O
static constexpr int Kdim = 4096;   // I = G*A
static constexpr int KC   = 1024;   // K chunk (4 chunks)
static constexpr int DQ0_BLOCKS = (Ndim * KC / 8) / 256;   // 2048 (chunk-0 dequant)
static constexpr int CVT_BLOCKS = (Mdim * Kdim / 8) / 256; // 4096

// ---------------- k1: zero flags, dequant W chunk 0 -> bf16, cast X -> bf16
__global__ __launch_bounds__(256)
void prep0(const float* __restrict__ binary, const float* __restrict__ alpha,
           const float* __restrict__ x, __bf16* __restrict__ w,
           __bf16* __restrict__ xb, unsigned int* __restrict__ ctr) {
  const int b = blockIdx.x;
  if (b == 0 && threadIdx.x < 4) ctr[threadIdx.x] = 0;
  if (b < DQ0_BLOCKS) {
    long e = ((long)b * 256 + threadIdx.x) * 8;   // flat over [4096][1024]
    int row = (int)(e >> 10);
    int colc = (int)(e & 1023);
    const float* al = alpha + ((long)row * 32 + (colc >> 7)) * 3;
    float a0 = al[0], a1 = al[1], a2 = al[2];
    const float4* q = (const float4*)(binary + ((long)row * Kdim + colc) * 3);
    float4 q0 = q[0], q1 = q[1], q2 = q[2], q3 = q[3], q4 = q[4], q5 = q[5];
    bf16x8 wv;
    wv[0] = (__bf16)(a0 * q0.x + a1 * q0.y + a2 * q0.z);
    wv[1] = (__bf16)(a0 * q0.w + a1 * q1.x + a2 * q1.y);
    wv[2] = (__bf16)(a0 * q1.z + a1 * q1.w + a2 * q2.x);
    wv[3] = (__bf16)(a0 * q2.y + a1 * q2.z + a2 * q2.w);
    wv[4] = (__bf16)(a0 * q3.x + a1 * q3.y + a2 * q3.z);
    wv[5] = (__bf16)(a0 * q3.w + a1 * q4.x + a2 * q4.y);
    wv[6] = (__bf16)(a0 * q4.z + a1 * q4.w + a2 * q5.x);
    wv[7] = (__bf16)(a0 * q5.y + a1 * q5.z + a2 * q5.w);
    *(bf16x8*)(w + (long)row * Kdim + colc) = wv;
  } else {
    long e = ((long)(b - DQ0_BLOCKS) * 256 + threadIdx.x) * 8;
    float4 v0 = *(const float4*)(x + e);
    float4 v1 = *(const float4*)(x + e + 4);
    bf16x8 r;
    r[0] = (__bf16)v0.x; r[1] = (__bf16)v0.y; r[2] = (__bf16)v0.z; r[3] = (__bf16)v0.w;
    r[4] = (__bf16)v1.x; r[5] = (__bf16)v1.y; r[6] = (__bf16)v1.z; r[7] = (__bf16)v1.w;
    *(bf16x8*)(xb + e) = r;
  }
}

// ---------------- k2: fused dequant+GEMM. 128x256 tile, per-wave 64x64,
// triple-buffered LDS, counted vmcnt gates, chunk-pipelined dequant.
static constexpr int BUF = 49152;        // 16KB A + 32KB B per buffer

__device__ __forceinline__ void g2l16(const void* g, void* l) {
  __builtin_amdgcn_global_load_lds(
      (const __attribute__((address_space(1))) void*)g,
      (__attribute__((address_space(3))) void*)l, 16, 0, 0);
}

#define BAR()    __builtin_amdgcn_s_barrier()
#define LGKM0()  asm volatile("s_waitcnt lgkmcnt(0)" ::: "memory")
#define SCHED0() __builtin_amdgcn_sched_barrier(0)
#define GATE(n)  asm volatile("s_waitcnt vmcnt(" #n ")" ::: "memory")

#define STAGE_A(t, bo) do { \
  _Pragma("unroll") for (int j_ = 0; j_ < 2; ++j_) \
    g2l16(baseA[j_] + (t) * 64, sm + (bo) + (w * 2 + j_) * 1024); \
} while (0)
#define STAGE_B(t, bo) do { \
  _Pragma("unroll") for (int j_ = 0; j_ < 4; ++j_) \
    g2l16(baseB[j_] + (t) * 64, sm + (bo) + 16384 + (w * 4 + j_) * 1024); \
} while (0)

#define LOAD_A4(dst, bo) do { \
  _Pragma("unroll") for (int m_ = 0; m_ < 4; ++m_) \
    _Pragma("unroll") for (int h_ = 0; h_ < 2; ++h_) \
      dst[m_][h_] = *(const bf16x8*)(sm + (bo) + aoffbase + m_ * 2048 + swz[h_]); \
} while (0)
#define LOAD_B2(dst, bo, n0_) do { \
  _Pragma("unroll") for (int n_ = 0; n_ < 2; ++n_) \
    _Pragma("unroll") for (int h_ = 0; h_ < 2; ++h_) \
      dst[n_][h_] = *(const bf16x8*)(sm + (bo) + boffbase + ((n0_) + n_) * 2048 + swz[h_]); \
} while (0)

#define MMA16(fa_, fb_, n0_) do { \
  __builtin_amdgcn_s_setprio(1); \
  _Pragma("unroll") for (int m_ = 0; m_ < 4; ++m_) \
    _Pragma("unroll") for (int n_ = 0; n_ < 2; ++n_) { \
      acc[m_][(n0_) + n_] = __builtin_amdgcn_mfma_f32_16x16x32_bf16( \
          fa_[m_][0], fb_[n_][0], acc[m_][(n0_) + n_], 0, 0, 0); \
      acc[m_][(n0_) + n_] = __builtin_amdgcn_mfma_f32_16x16x32_bf16( \
          fa_[m_][1], fb_[n_][1], acc[m_][(n0_) + n_], 0, 0, 0); \
    } \
  __builtin_amdgcn_s_setprio(0); \
} while (0)

// dequant batch: inline-asm loads => EXACT vmcnt op counts (A=6, B=3, store=1)
#define ISSUE_A(cn_, tq_) do { \
  long wf_ = (((long)(tq_) * 256 + bid) * 512 + tid) * 8; \
  int row_ = (int)(wf_ >> 10); \
  int col_ = (cn_) * 1024 + (int)(wf_ & 1023); \
  dq_b = binary + ((long)row_ * Kdim + col_) * 3; \
  dq_w = Bw + (long)row_ * Kdim + col_; \
  dq_a = alpha + ((long)row_ * 32 + (col_ >> 7)) * 3; \
  asm volatile("global_load_dwordx4 %0, %1, off"           : "=v"(q0) : "v"(dq_b) : "memory"); \
  asm volatile("global_load_dwordx4 %0, %1, off offset:16" : "=v"(q1) : "v"(dq_b) : "memory"); \
  asm volatile("global_load_dwordx4 %0, %1, off offset:32" : "=v"(q2) : "v"(dq_b) : "memory"); \
  asm volatile("global_load_dword %0, %1, off"             : "=v"(a0) : "v"(dq_a) : "memory"); \
  asm volatile("global_load_dword %0, %1, off offset:4"    : "=v"(a1) : "v"(dq_a) : "memory"); \
  asm volatile("global_load_dword %0, %1, off offset:8"    : "=v"(a2) : "v"(dq_a) : "memory"); \
} while (0)
#define ISSUE_B() do { \
  asm volatile("global_load_dwordx4 %0, %1, off offset:48" : "=v"(q3) : "v"(dq_b) : "memory"); \
  asm volatile("global_load_dwordx4 %0, %1, off offset:64" : "=v"(q4) : "v"(dq_b) : "memory"); \
  asm volatile("global_load_dwordx4 %0, %1, off offset:80" : "=v"(q5) : "v"(dq_b) : "memory"); \
} while (0)
#define CONSUME(g_) do { \
  GATE(g_); SCHED0(); \
  bf16x8 wv_; \
  wv_[0] = (__bf16)(a0 * q0.x + a1 * q0.y + a2 * q0.z); \
  wv_[1] = (__bf16)(a0 * q0.w + a1 * q1.x + a2 * q1.y); \
  wv_[2] = (__bf16)(a0 * q1.z + a1 * q1.w + a2 * q2.x); \
  wv_[3] = (__bf16)(a0 * q2.y + a1 * q2.z + a2 * q2.w); \
  wv_[4] = (__bf16)(a0 * q3.x + a1 * q3.y + a2 * q3.z); \
  wv_[5] = (__bf16)(a0 * q3.w + a1 * q4.x + a2 * q4.y); \
  wv_[6] = (__bf16)(a0 * q4.z + a1 * q4.w + a2 * q5.x); \
  wv_[7] = (__bf16)(a0 * q5.y + a1 * q5.z + a2 * q5.w); \
  *(bf16x8*)dq_w = wv_; \
} while (0)

// one K-tile: P1 {dsA+dsB01, stageA(t+2), MMA} ; P2 {dsB23, stageB(t+2), gate, MMA}
#define TILE(tg_, PF_, PRE_, POST_, GATE_STMT) do { \
  PRE_ \
  LOAD_A4(fa, ba); LOAD_B2(fb01, ba, 0); \
  if (PF_) STAGE_A((tg_) + 2, bc); \
  BAR(); LGKM0(); SCHED0(); \
  MMA16(fa, fb01, 0); \
  BAR(); \
  LOAD_B2(fb23, ba, 2); \
  if (PF_) STAGE_B((tg_) + 2, bc); \
  POST_ \
  GATE_STMT; \
  BAR(); LGKM0(); SCHED0(); \
  MMA16(fa, fb23, 2); \
  BAR(); \
  { int tmp_ = ba; ba = bb; bb = bc; bc = tmp_; } \
} while (0)

__global__ __launch_bounds__(512, 2)
void gemm5(const __bf16* __restrict__ A, __bf16* __restrict__ Bw,
           const float* __restrict__ bias, float* __restrict__ out,
           const float* __restrict__ binary, const float* __restrict__ alpha,
           unsigned int* __restrict__ ctr) {
  __shared__ __align__(128) char sm[3 * BUF];   // 144 KB -> 1 block/CU (spin-safe)
  const int tid = threadIdx.x, lane = tid & 63, w = tid >> 6;
  const int wm = w >> 2, wn = w & 3;            // 2M x 4N waves; per-wave 64x64
  const int bid = blockIdx.x;

  const int logical = (bid & 7) * 32 + (bid >> 3);   // XCD swizzle (bijective)
  const int tm = logical & 15;                  // 16 M-tiles (BM=128)
  const int tn = logical >> 4;                  // 16 N-tiles (BN=256)

  const int rlo = lane >> 3;
  const int gsw = (lane & 7) ^ rlo;             // inverse-swizzle granule [rule 21]
  const __bf16* baseA[2];
  const __bf16* baseB[4];
#pragma unroll
  for (int j = 0; j < 2; ++j)
    baseA[j] = A + (long)(tm * 128 + w * 16 + j * 8 + rlo) * Kdim + gsw * 8;
#pragma unroll
  for (int j = 0; j < 4; ++j)
    baseB[j] = Bw + (long)(tn * 256 + w * 32 + j * 8 + rlo) * Kdim + gsw * 8;

  int swz[2];
#pragma unroll
  for (int h = 0; h < 2; ++h)
    swz[h] = (((h * 4 + (lane >> 4)) ^ (lane & 7)) << 4);
  const int aoffbase = (wm * 64 + (lane & 15)) * 128;
  const int boffbase = 16384 + (wn * 64 + (lane & 15)) * 128;

  f32x4 acc[4][4] = {};
  bf16x8 fa[4][2], fb01[2][2], fb23[2][2];
  int ba = 0, bb = BUF, bc = 2 * BUF;

  // dequant batch state
  const float* dq_b; const float* dq_a; __bf16* dq_w;
  float4 q0, q1, q2, q3, q4, q5; float a0, a1, a2;

  for (int c = 0; c < 4; ++c) {
    if (c > 0) {
      BAR();
      if (tid == 0) {
        while (__hip_atomic_load(&ctr[c], __ATOMIC_ACQUIRE, __HIP_MEMORY_SCOPE_AGENT) < 256u)
          __builtin_amdgcn_s_sleep(4);
      }
      BAR();
    }
    const int tg0 = c * 16;
    // chunk prologue: tiles tg0 -> ba, tg0+1 -> bb
    STAGE_A(tg0, ba); STAGE_B(tg0, ba);
    STAGE_A(tg0 + 1, bb); STAGE_B(tg0 + 1, bb);
    GATE(6); BAR();

    if (c < 3) {
      const int cn = c + 1;
      TILE(tg0 + 0,  1, , ISSUE_A(cn, 0);, GATE(12));
      TILE(tg0 + 1,  1, , ISSUE_B();,      GATE(15));
      TILE(tg0 + 2,  1, ,               ,  GATE(9));
      TILE(tg0 + 3,  1, CONSUME(6);, ,     GATE(7));
      TILE(tg0 + 4,  1, , ISSUE_A(cn, 1);, GATE(12));
      TILE(tg0 + 5,  1, , ISSUE_B();,      GATE(15));
      TILE(tg0 + 6,  1, ,               ,  GATE(9));
      TILE(tg0 + 7,  1, CONSUME(6);, ,     GATE(7));
      TILE(tg0 + 8,  1, , ISSUE_A(cn, 2);, GATE(12));
      TILE(tg0 + 9,  1, , ISSUE_B();,      GATE(15));
      TILE(tg0 + 10, 1, ,               ,  GATE(9));
      TILE(tg0 + 11, 1, CONSUME(6);, ,     GATE(7));
      TILE(tg0 + 12, 1, , ISSUE_A(cn, 3);, GATE(12));
      TILE(tg0 + 13, 1, , ISSUE_B();,      GATE(15));
      TILE(tg0 + 14, 0, ,               ,  GATE(3));
      TILE(tg0 + 15, 0, CONSUME(0);, ,     GATE(0));
      if (tid == 0)
        __hip_atomic_fetch_add(&ctr[c + 1], 1u, __ATOMIC_RELEASE, __HIP_MEMORY_SCOPE_AGENT);
    } else {
      TILE(tg0 + 0,  1, , , GATE(6));
      TILE(tg0 + 1,  1, , , GATE(6));
      TILE(tg0 + 2,  1, , , GATE(6));
      TILE(tg0 + 3,  1, , , GATE(6));
      TILE(tg0 + 4,  1, , , GATE(6));
      TILE(tg0 + 5,  1, , , GATE(6));
      TILE(tg0 + 6,  1, , , GATE(6));
      TILE(tg0 + 7,  1, , , GATE(6));
      TILE(tg0 + 8,  1, , , GATE(6));
      TILE(tg0 + 9,  1, , , GATE(6));
      TILE(tg0 + 10, 1, , , GATE(6));
      TILE(tg0 + 11, 1, , , GATE(6));
      TILE(tg0 + 12, 1, , , GATE(6));
      TILE(tg0 + 13, 1, , , GATE(6));
      TILE(tg0 + 14, 0, , , GATE(0));
      TILE(tg0 + 15, 0, , , GATE(0));
    }
  }

  // epilogue: acc -> LDS [128][260] f32, then coalesced float4 stores + bias
  float* lf = (float*)sm;
  const int r4 = (lane >> 4) * 4;
  const int cl = lane & 15;
#pragma unroll
  for (int m = 0; m < 4; ++m)
#pragma unroll
    for (int n = 0; n < 4; ++n)
#pragma unroll
      for (int r = 0; r < 4; ++r) {
        int row = wm * 64 + m * 16 + r4 + r;
        int col = wn * 64 + n * 16 + cl;
        lf[row * 260 + col] = acc[m][n][r];
      }
  __syncthreads();
#pragma unroll
  for (int i = 0; i < 16; ++i) {
    int idx = tid + i * 512;
    int row = idx >> 6;
    int c4 = idx & 63;
    f32x4 v = *(const f32x4*)(lf + row * 260 + c4 * 4);
    float4 bv = *(const float4*)(bias + tn * 256 + c4 * 4);
    v[0] += bv.x; v[1] += bv.y; v[2] += bv.z; v[3] += bv.w;
    *(f32x4*)(out + (long)(tm * 128 + row) * Ndim + tn * 256 + c4 * 4) = v;
  }
}

extern "C" void kernel_launch(void* const* d_in, const int* in_sizes, int n_in,
                              void* d_out, int out_size, void* d_ws, size_t ws_size,
                              hipStream_t stream) {
  const float* x      = (const float*)d_in[0];
  const float* binary = (const float*)d_in[1];
  const float* alpha  = (const float*)d_in[2];
  const float* bias   = (const float*)d_in[3];
  float* out = (float*)d_out;

  __bf16* wb = (__bf16*)d_ws;                              // 32 MB  W bf16 [N][K]
  __bf16* xb = wb + (size_t)Ndim * Kdim;                   // 16 MB  X bf16 [M][K]
  unsigned int* ctr = (unsigned int*)(xb + (size_t)Mdim * Kdim);  // 16 B flags

  prep0<<<dim3(DQ0_BLOCKS + CVT_BLOCKS), 256, 0, stream>>>(binary, alpha, x, wb, xb, ctr);
  gemm5<<<dim3(256), 512, 0, stream>>>(xb, wb, bias, out, binary, alpha, ctr);
}

// Round 7
// 123.258 us; speedup vs baseline: 2.2570x; 2.2570x over previous
//
#include <hip/hip_runtime.h>
#include <hip/hip_bf16.h>
#include <stdint.h>

typedef __bf16 bf16x8 __attribute__((ext_vector_type(8)));
typedef float  f32x4  __attribute__((ext_vector_type(4)));

static constexpr int Mdim = 2048;   // B*S
static constexpr int Ndim = 4096;   // O
static constexpr int Kdim = 4096;   // I = G*A
static constexpr int DQ_BLOCKS = (Ndim * Kdim / 8) / 256;        // 8192
static constexpr int CVT_BLOCKS = (Mdim * Kdim / 8) / 256;       // 4096

// ---------------- fused prep: dequant W -> bf16 [O][K], cast X -> bf16 [M][K]
__global__ __launch_bounds__(256)
void prep(const float* __restrict__ binary, const float* __restrict__ alpha,
          const float* __restrict__ x, __bf16* __restrict__ w,
          __bf16* __restrict__ xb) {
  const int b = blockIdx.x;
  if (b < DQ_BLOCKS) {
    long e = ((long)b * 256 + threadIdx.x) * 8;       // 8 weights/thread
    int o = (int)(e >> 12);
    int g = (int)((e & 4095) >> 7);
    const float* al = alpha + ((long)o * 32 + g) * 3;
    float a0 = al[0], a1 = al[1], a2 = al[2];
    const float4* q = (const float4*)(binary + e * 3);  // 96B
    float4 q0 = q[0], q1 = q[1], q2 = q[2], q3 = q[3], q4 = q[4], q5 = q[5];
    bf16x8 wv;
    wv[0] = (__bf16)(a0 * q0.x + a1 * q0.y + a2 * q0.z);
    wv[1] = (__bf16)(a0 * q0.w + a1 * q1.x + a2 * q1.y);
    wv[2] = (__bf16)(a0 * q1.z + a1 * q1.w + a2 * q2.x);
    wv[3] = (__bf16)(a0 * q2.y + a1 * q2.z + a2 * q2.w);
    wv[4] = (__bf16)(a0 * q3.x + a1 * q3.y + a2 * q3.z);
    wv[5] = (__bf16)(a0 * q3.w + a1 * q4.x + a2 * q4.y);
    wv[6] = (__bf16)(a0 * q4.z + a1 * q4.w + a2 * q5.x);
    wv[7] = (__bf16)(a0 * q5.y + a1 * q5.z + a2 * q5.w);
    *(bf16x8*)(w + e) = wv;
  } else {
    long e = ((long)(b - DQ_BLOCKS) * 256 + threadIdx.x) * 8;
    float4 v0 = *(const float4*)(x + e);
    float4 v1 = *(const float4*)(x + e + 4);
    bf16x8 r;
    r[0] = (__bf16)v0.x; r[1] = (__bf16)v0.y; r[2] = (__bf16)v0.z; r[3] = (__bf16)v0.w;
    r[4] = (__bf16)v1.x; r[5] = (__bf16)v1.y; r[6] = (__bf16)v1.z; r[7] = (__bf16)v1.w;
    *(bf16x8*)(xb + e) = r;
  }
}

// ---------------- split-K reduce: out = P0 + P1 + bias  (bf16 partials)
__global__ __launch_bounds__(256)
void reduce_add(const __bf16* __restrict__ p, const float* __restrict__ bias,
                float* __restrict__ out) {
  long e = ((long)blockIdx.x * 256 + threadIdx.x) * 8;
  bf16x8 a = *(const bf16x8*)(p + e);
  bf16x8 c = *(const bf16x8*)(p + (long)Mdim * Ndim + e);
  int col = (int)(e & (Ndim - 1));
  float4 bv0 = *(const float4*)(bias + col);
  float4 bv1 = *(const float4*)(bias + col + 4);
  float4 r0, r1;
  r0.x = (float)a[0] + (float)c[0] + bv0.x;
  r0.y = (float)a[1] + (float)c[1] + bv0.y;
  r0.z = (float)a[2] + (float)c[2] + bv0.z;
  r0.w = (float)a[3] + (float)c[3] + bv0.w;
  r1.x = (float)a[4] + (float)c[4] + bv1.x;
  r1.y = (float)a[5] + (float)c[5] + bv1.y;
  r1.z = (float)a[6] + (float)c[6] + bv1.z;
  r1.w = (float)a[7] + (float)c[7] + bv1.w;
  *(float4*)(out + e) = r0;
  *(float4*)(out + e + 4) = r1;
}

// ---------------- 256x256 split-K=2 GEMM, 8 waves (2Mx4N, wave 128x64),
// BK=64, double-buffered LDS (128KB), 8 phases / 2 tiles, GATE(8) steady.
static constexpr int KSLICE = 2048;
static constexpr int NT = KSLICE / 64;   // 32 K-tiles per slice
static constexpr int HB = 65536;         // bytes per buffer (A 32KB + B 32KB)

__device__ __forceinline__ void g2l16(const void* g, void* l) {
  __builtin_amdgcn_global_load_lds(
      (const __attribute__((address_space(1))) void*)g,
      (__attribute__((address_space(3))) void*)l, 16, 0, 0);
}

#define BAR()    __builtin_amdgcn_s_barrier()
#define LGKM0()  asm volatile("s_waitcnt lgkmcnt(0)" ::: "memory")
#define SCHED0() __builtin_amdgcn_sched_barrier(0)
#define GATE8()  asm volatile("s_waitcnt vmcnt(8)" ::: "memory")
#define GATE0()  asm volatile("s_waitcnt vmcnt(0)" ::: "memory")

// Stage units (2 x g2l16 each).  LDS linear dest (wave-uniform base + lane*16);
// global source pre-swizzled (granule ^= row&7) so read-side XOR matches. [rule 21]
// A rows (within 256): A1={0-63,128-191}  A2={64-127,192-255}
#define STAGE_A1(t, bo) do { \
  g2l16(baseA +                 (long)(t) * 64, sm + (bo) +     0 + w * 1024); \
  g2l16(baseA + 128L * Kdim   + (long)(t) * 64, sm + (bo) + 16384 + w * 1024); \
} while (0)
#define STAGE_A2(t, bo) do { \
  g2l16(baseA +  64L * Kdim   + (long)(t) * 64, sm + (bo) +  8192 + w * 1024); \
  g2l16(baseA + 192L * Kdim   + (long)(t) * 64, sm + (bo) + 24576 + w * 1024); \
} while (0)
// B rows (within 256): strips of 64 per wn; B1 = strip rows 0-31, B2 = 32-63
#define STAGE_B1(t, bo) do { \
  g2l16(baseB +                 (long)(t) * 64, sm + (bo) + 32768 + bq * 1024); \
  g2l16(baseB +   8L * Kdim   + (long)(t) * 64, sm + (bo) + 32768 + bq * 1024 + 1024); \
} while (0)
#define STAGE_B2(t, bo) do { \
  g2l16(baseB +  32L * Kdim   + (long)(t) * 64, sm + (bo) + 32768 + bq * 1024 + 4096); \
  g2l16(baseB +  40L * Kdim   + (long)(t) * 64, sm + (bo) + 32768 + bq * 1024 + 5120); \
} while (0)

#define LOAD_A4(dst, bo, m0_) do { \
  _Pragma("unroll") for (int m_ = 0; m_ < 4; ++m_) \
    _Pragma("unroll") for (int h_ = 0; h_ < 2; ++h_) \
      dst[m_][h_] = *(const bf16x8*)(sm + (bo) + aoffbase + ((m0_) + m_) * 2048 + swz[h_]); \
} while (0)
#define LOAD_B2(dst, bo, n0_) do { \
  _Pragma("unroll") for (int n_ = 0; n_ < 2; ++n_) \
    _Pragma("unroll") for (int h_ = 0; h_ < 2; ++h_) \
      dst[n_][h_] = *(const bf16x8*)(sm + (bo) + boffbase + ((n0_) + n_) * 2048 + swz[h_]); \
} while (0)

#define MMA8(fa_, fb_, m0_, n0_) do { \
  __builtin_amdgcn_s_setprio(1); \
  _Pragma("unroll") for (int m_ = 0; m_ < 4; ++m_) \
    _Pragma("unroll") for (int n_ = 0; n_ < 2; ++n_) { \
      acc[(m0_) + m_][(n0_) + n_] = __builtin_amdgcn_mfma_f32_16x16x32_bf16( \
          fa_[m_][0], fb_[n_][0], acc[(m0_) + m_][(n0_) + n_], 0, 0, 0); \
      acc[(m0_) + m_][(n0_) + n_] = __builtin_amdgcn_mfma_f32_16x16x32_bf16( \
          fa_[m_][1], fb_[n_][1], acc[(m0_) + m_][(n0_) + n_], 0, 0, 0); \
    } \
  __builtin_amdgcn_s_setprio(0); \
} while (0)

// half-K-tile (4 phases) for tile t in buffer bo; prefetches tile t+2 into bo
#define KTILE(t_, bo, PF_, LASTGATE) do { \
  /* P1 */ \
  LOAD_A4(fa, bo, 0); LOAD_B2(fb01, bo, 0); \
  BAR(); LGKM0(); SCHED0(); \
  MMA8(fa, fb01, 0, 0); \
  BAR(); \
  /* P2 */ \
  LOAD_B2(fb23, bo, 2); \
  if (PF_) { STAGE_A1((t_) + 2, bo); STAGE_B1((t_) + 2, bo); } \
  BAR(); LGKM0(); SCHED0(); \
  MMA8(fa, fb23, 0, 2); \
  BAR(); \
  /* P3 */ \
  LOAD_A4(fa, bo, 4); \
  if (PF_) STAGE_B2((t_) + 2, bo); \
  BAR(); LGKM0(); SCHED0(); \
  MMA8(fa, fb01, 4, 0); \
  BAR(); \
  /* P4 */ \
  if (PF_) { STAGE_A2((t_) + 2, bo); GATE8(); } else { LASTGATE; } \
  BAR(); \
  MMA8(fa, fb23, 4, 2); \
  BAR(); \
} while (0)

__global__ __launch_bounds__(512, 2)
void gemm256(const __bf16* __restrict__ A, const __bf16* __restrict__ Bw,
             __bf16* __restrict__ P) {
  __shared__ __align__(128) char sm[2 * HB];   // 128 KB
  const int tid = threadIdx.x, lane = tid & 63, w = tid >> 6;
  const int wm = w >> 2, wn = w & 3;           // wave tile 128x64

  // XCD-aware bijective swizzle (256 blocks = 8 XCD x 32)
  const int bid = blockIdx.x;
  const int logical = (bid & 7) * 32 + (bid >> 3);
  const int ks = logical >> 7;                 // split-K slice
  const int tile = logical & 127;
  const int tm = tile & 7, tn = tile >> 3;     // 8 x 16 tiles of 256x256
  const int kbase = ks * KSLICE;

  __bf16* Pout = P + (long)ks * Mdim * Ndim;

  // staging bases (pre-swizzled granule: gsw = (lane&7) ^ (lane>>3))
  const int rlo = lane >> 3;
  const int gsw = (lane & 7) ^ rlo;
  const __bf16* baseA = A + (long)(tm * 256 + w * 8 + rlo) * Kdim + kbase + gsw * 8;
  const __bf16* baseB = Bw + (long)(tn * 256 + (w >> 1) * 64 + (w & 1) * 16 + rlo) * Kdim
                        + kbase + gsw * 8;
  const int bq = (w >> 1) * 8 + (w & 1) * 2;   // B LDS KB-slot base

  // read-side swizzled offsets
  int swz[2];
#pragma unroll
  for (int h = 0; h < 2; ++h)
    swz[h] = (((h * 4 + (lane >> 4)) ^ (lane & 7)) << 4);
  const int aoffbase = (wm * 128 + (lane & 15)) * 128;
  const int boffbase = 32768 + (wn * 64 + (lane & 15)) * 128;

  f32x4 acc[8][4] = {};
  bf16x8 fa[4][2], fb01[2][2], fb23[2][2];

  // prologue: tile0 -> buf0 (8 ops), tile1 -> buf1 (8 ops); wait tile0
  STAGE_A1(0, 0);  STAGE_B1(0, 0);  STAGE_B2(0, 0);  STAGE_A2(0, 0);
  STAGE_A1(1, HB); STAGE_B1(1, HB); STAGE_B2(1, HB); STAGE_A2(1, HB);
  GATE8();
  BAR();

  for (int i = 0; i < NT / 2; ++i) {
    const int t0 = 2 * i, t1 = 2 * i + 1;
    const bool pf = (i < NT / 2 - 1);
    KTILE(t0, 0,  pf, GATE0());   // phases 1-4 (needs t1 at P4)
    KTILE(t1, HB, pf, GATE0());   // phases 5-8 (needs t0+2 at P8)
  }

  // epilogue: C/D layout col=lane&15, row=(lane>>4)*4+reg ; bf16 partials
  const int r4 = (lane >> 4) * 4;
  const int cl = lane & 15;
#pragma unroll
  for (int m = 0; m < 8; ++m)
#pragma unroll
    for (int n = 0; n < 4; ++n)
#pragma unroll
      for (int r = 0; r < 4; ++r) {
        int row = tm * 256 + wm * 128 + m * 16 + r4 + r;
        int col = tn * 256 + wn * 64 + n * 16 + cl;
        Pout[(long)row * Ndim + col] = (__bf16)acc[m][n][r];
      }
}

extern "C" void kernel_launch(void* const* d_in, const int* in_sizes, int n_in,
                              void* d_out, int out_size, void* d_ws, size_t ws_size,
                              hipStream_t stream) {
  const float* x      = (const float*)d_in[0];
  const float* binary = (const float*)d_in[1];
  const float* alpha  = (const float*)d_in[2];
  const float* bias   = (const float*)d_in[3];
  float* out = (float*)d_out;

  __bf16* wb = (__bf16*)d_ws;                              // 32 MB  W bf16 [N][K]
  __bf16* xb = wb + (size_t)Ndim * Kdim;                   // 16 MB  X bf16 [M][K]
  __bf16* pp = xb + (size_t)Mdim * Kdim;                   // 32 MB  partials bf16 [2][M][N]

  prep<<<dim3(DQ_BLOCKS + CVT_BLOCKS), 256, 0, stream>>>(binary, alpha, x, wb, xb);
  gemm256<<<dim3(256), 512, 0, stream>>>(xb, wb, pp);
  reduce_add<<<dim3(Mdim * Ndim / 8 / 256), 256, 0, stream>>>(pp, bias, out);
}